// Round 1
// baseline (44.399 us; speedup 1.0000x reference)
//
#include <hip/hip_runtime.h>
#include <math.h>

#define IN_H 104
#define IN_W 104
#define NA 3
#define BS 16
#define NT 50
#define SUB 6
#define FEPS 1e-7f
#define CELLS (NA * IN_H * IN_W)   // 32448

// scaled anchors = ANCHORS / 8  (stride = 832/104 = 8)
__constant__ float c_aw[9] = {1.25f, 2.0f, 4.125f, 3.75f, 7.75f, 7.375f, 14.5f, 19.5f, 46.625f};
__constant__ float c_ah[9] = {1.625f, 3.75f, 2.875f, 7.625f, 5.625f, 14.875f, 11.25f, 24.75f, 40.75f};

__device__ __forceinline__ float sigmoidf_(float v) {
    return 1.0f / (1.0f + __expf(-v) * 0.0f + expf(-v));  // keep exact expf
}

__global__ __launch_bounds__(256) void yolo_loss_kernel(
    const float* __restrict__ in,   // (16, 18, 104, 104)
    const float* __restrict__ tgt,  // (16, 50, 5)
    float* __restrict__ out)        // (1,)
{
    const int b   = blockIdx.y;
    const int tid = threadIdx.x;

    // per-target staged data (this batch only)
    __shared__ float s_bx1[NT], s_by1[NT], s_bx2[NT], s_by2[NT], s_areab[NT];
    __shared__ int   s_code[NT];
    __shared__ float s_tx[NT], s_ty[NT], s_tw[NT], s_th[NT], s_bls[NT];

    if (tid < NT) {
        const float* tp = tgt + (size_t)(b * NT + tid) * 5;
        float t0 = tp[0], t1 = tp[1], t2 = tp[2], t3 = tp[3];
        float gx = t0 * IN_W, gy = t1 * IN_H, gw = t2 * IN_W, gh = t3 * IN_H;

        // anchor argmax (first-max tie-break, like jnp.argmax)
        int bn = 0; float best = -1e30f;
        #pragma unroll
        for (int k = 0; k < 9; ++k) {
            float aw = c_aw[k], ah = c_ah[k];
            float inter = fminf(gw, aw) * fminf(gh, ah);
            float uni   = gw * gh + aw * ah - inter;
            float r = inter / uni;
            if (r > best) { best = r; bn = k; }
        }
        int gi = (int)floorf(gx);
        int gj = (int)floorf(gy);
        bool valid = (bn >= SUB) && (bn < SUB + 3) &&
                     (gj < IN_H) && (gi < IN_W) && (gi >= 0) && (gj >= 0);
        s_code[tid] = valid ? ((bn - SUB) * IN_H * IN_W + gj * IN_W + gi) : -1;
        s_tx[tid]  = gx - floorf(gx);
        s_ty[tid]  = gy - floorf(gy);
        s_tw[tid]  = logf(fmaxf(gw, FEPS) / c_aw[bn]);
        s_th[tid]  = logf(fmaxf(gh, FEPS) / c_ah[bn]);
        s_bls[tid] = 2.0f - t2 * t3;
        s_bx1[tid] = gx - gw * 0.5f;  s_by1[tid] = gy - gh * 0.5f;
        s_bx2[tid] = gx + gw * 0.5f;  s_by2[tid] = gy + gh * 0.5f;
        s_areab[tid] = gw * gh;
    }
    __syncthreads();

    const int cell = blockIdx.x * 256 + tid;
    float contrib = 0.0f;

    if (cell < CELLS) {
        const int a   = cell / (IN_H * IN_W);
        const int rem = cell % (IN_H * IN_W);
        const int j   = rem / IN_W;
        const int i   = rem % IN_W;

        const size_t cs   = (size_t)IN_H * IN_W;
        const size_t base = (((size_t)b * 18 + (size_t)a * 6) * IN_H + j) * IN_W + i;

        const float v0 = in[base];
        const float v1 = in[base + cs];
        const float v2 = in[base + 2 * cs];
        const float v3 = in[base + 3 * cs];
        const float v4 = in[base + 4 * cs];
        const float v5 = in[base + 5 * cs];

        const float sx   = 1.0f / (1.0f + expf(-v0));
        const float sy   = 1.0f / (1.0f + expf(-v1));
        const float conf = 1.0f / (1.0f + expf(-v4));

        const float pw = expf(v2) * c_aw[SUB + a];
        const float ph = expf(v3) * c_ah[SUB + a];
        const float px = sx + (float)i;
        const float py = sy + (float)j;

        const float ax1 = px - pw * 0.5f, ay1 = py - ph * 0.5f;
        const float ax2 = px + pw * 0.5f, ay2 = py + ph * 0.5f;
        const float areaa = pw * ph;

        const int mycode = cell;
        int   win   = -1;
        float worst = -1e30f;   // max over t of (2*inter - union); noobj iff <= 0

        for (int t = 0; t < NT; ++t) {
            float mnx = fmaxf(ax1, s_bx1[t]);
            float mny = fmaxf(ay1, s_by1[t]);
            float mxx = fminf(ax2, s_bx2[t]);
            float mxy = fminf(ay2, s_by2[t]);
            float iw = fmaxf(mxx - mnx, 0.0f);
            float ih = fmaxf(mxy - mny, 0.0f);
            float inter = iw * ih;
            float uni   = areaa + s_areab[t] - inter;
            worst = fmaxf(worst, 2.0f * inter - uni);
            win = (s_code[t] == mycode) ? t : win;  // last match wins (XLA set order)
        }

        const float conf_c = fminf(fmaxf(conf, FEPS), 1.0f - FEPS);

        if (win >= 0) {
            // masked cell: coord + size + obj-conf + cls losses
            const float x_c = fminf(fmaxf(sx, FEPS), 1.0f - FEPS);
            const float y_c = fminf(fmaxf(sy, FEPS), 1.0f - FEPS);
            const float scls  = 1.0f / (1.0f + expf(-v5));
            const float cls_c = fminf(fmaxf(scls, FEPS), 1.0f - FEPS);

            const float txv = s_tx[win], tyv = s_ty[win];
            const float twv = s_tw[win], thv = s_th[win];
            const float bls = s_bls[win];

            const float bx = -txv * logf(x_c) - (1.0f - txv) * logf(1.0f - x_c);
            const float by = -tyv * logf(y_c) - (1.0f - tyv) * logf(1.0f - y_c);
            const float dw = v2 - twv, dh = v3 - thv;

            contrib = (bx + by) * bls
                    + 0.5f * (dw * dw + dh * dh) * bls
                    - logf(conf_c)     // bce(conf, 1) * mask
                    - logf(cls_c);     // bce(cls, 1)  * mask  (tcls=1, NUM_CLASSES=1)
        } else if (worst <= 0.0f) {
            contrib = -logf(1.0f - conf_c);  // bce(conf, 0) * noobj
        }
        contrib *= (1.0f / (float)BS);
    }

    // block reduction: wave64 shuffle + LDS across 4 waves
    for (int o = 32; o > 0; o >>= 1)
        contrib += __shfl_down(contrib, o, 64);

    __shared__ float s_part[4];
    if ((tid & 63) == 0) s_part[tid >> 6] = contrib;
    __syncthreads();
    if (tid == 0) {
        float tot = s_part[0] + s_part[1] + s_part[2] + s_part[3];
        atomicAdd(out, tot);
    }
}

extern "C" void kernel_launch(void* const* d_in, const int* in_sizes, int n_in,
                              void* d_out, int out_size, void* d_ws, size_t ws_size,
                              hipStream_t stream) {
    const float* in  = (const float*)d_in[0];   // (16, 18, 104, 104) f32
    const float* tgt = (const float*)d_in[1];   // (16, 50, 5) f32
    float* out = (float*)d_out;

    hipMemsetAsync(out, 0, sizeof(float), stream);

    dim3 grid((CELLS + 255) / 256, BS);  // (127, 16)
    yolo_loss_kernel<<<grid, 256, 0, stream>>>(in, tgt, out);
}

// Round 2
// 31.809 us; speedup vs baseline: 1.3958x; 1.3958x over previous
//
#include <hip/hip_runtime.h>
#include <math.h>

#define IN_H 104
#define IN_W 104
#define BSZ 16
#define NT 50
#define SUB 6
#define FEPS 1e-7f
#define CS (IN_H * IN_W)            // 10816
#define CELLS (3 * CS)              // 32448
#define DBLK 256
#define CPT 2
#define NBX ((CELLS + DBLK * CPT - 1) / (DBLK * CPT))   // 64
#define NPART (BSZ * NBX)           // 1024

// scaled anchors = ANCHORS / 8  (stride = 832/104 = 8)
__constant__ float c_aw[9] = {1.25f, 2.0f, 4.125f, 3.75f, 7.75f, 7.375f, 14.5f, 19.5f, 46.625f};
__constant__ float c_ah[9] = {1.625f, 3.75f, 2.875f, 7.625f, 5.625f, 14.875f, 11.25f, 24.75f, 40.75f};

__device__ __forceinline__ float clampp(float v) {
    return fminf(fmaxf(v, FEPS), 1.0f - FEPS);
}

// >0  <=>  IoU(pred, box) > 0.5      (3*inter > areaA + areaB  <=>  2*inter > union)
__device__ __forceinline__ float iou_score(float4 bx, float ax1, float ay1,
                                           float ax2, float ay2, float areaa) {
    float mnx = fmaxf(ax1, bx.x), mny = fmaxf(ay1, bx.y);
    float mxx = fminf(ax2, bx.z), mxy = fminf(ay2, bx.w);
    float iw = fmaxf(mxx - mnx, 0.0f), ih = fmaxf(mxy - mny, 0.0f);
    float inter = iw * ih;
    float areab = (bx.z - bx.x) * (bx.w - bx.y);
    return 3.0f * inter - (areaa + areab);
}

// ---------------- prep: per-target boxes + winner (masked-cell) losses ----------------
__global__ __launch_bounds__(64) void prep_kernel(const float* __restrict__ in,
                                                  const float* __restrict__ tgt,
                                                  float4* __restrict__ g_box,
                                                  float* __restrict__ g_extra) {
    const int b = blockIdx.x;
    const int t = threadIdx.x;

    __shared__ float4 s_box[NT];
    __shared__ int    s_code[NT];

    int   code = -1, bn = 0, gi = 0, gj = 0;
    float gx = 0.f, gy = 0.f, gw = 0.f, gh = 0.f, t2v = 0.f, t3v = 0.f;

    if (t < NT) {
        const float* tp = tgt + (size_t)(b * NT + t) * 5;
        float t0 = tp[0], t1 = tp[1];
        t2v = tp[2]; t3v = tp[3];
        gx = t0 * IN_W; gy = t1 * IN_H; gw = t2v * IN_W; gh = t3v * IN_H;

        float best = -1e30f;
        #pragma unroll
        for (int k = 0; k < 9; ++k) {
            float aw = c_aw[k], ah = c_ah[k];
            float inter = fminf(gw, aw) * fminf(gh, ah);
            float uni   = gw * gh + aw * ah - inter;
            float r = inter / uni;
            if (r > best) { best = r; bn = k; }
        }
        gi = (int)floorf(gx);
        gj = (int)floorf(gy);
        bool valid = (bn >= SUB) && (bn < SUB + 3) &&
                     (gj < IN_H) && (gi < IN_W) && (gi >= 0) && (gj >= 0);
        code = valid ? ((bn - SUB) * CS + gj * IN_W + gi) : -1;

        float4 box = make_float4(gx - gw * 0.5f, gy - gh * 0.5f,
                                 gx + gw * 0.5f, gy + gh * 0.5f);
        s_box[t]  = box;
        s_code[t] = code;
        g_box[b * NT + t] = box;
    }
    __syncthreads();

    if (t < NT) {
        // last-wins dedup: t is the winner iff valid and no later target has same code
        bool winner = (code >= 0);
        for (int u = t + 1; u < NT; ++u) winner = winner && (s_code[u] != code);

        float extra = 0.0f;
        if (winner) {
            const int a = bn - SUB;
            const size_t base = (((size_t)b * 18 + (size_t)a * 6) * IN_H + gj) * IN_W + gi;
            float v0 = in[base];
            float v1 = in[base + CS];
            float v2 = in[base + 2 * CS];
            float v3 = in[base + 3 * CS];
            float v4 = in[base + 4 * CS];
            float v5 = in[base + 5 * CS];

            float sx   = 1.0f / (1.0f + expf(-v0));
            float sy   = 1.0f / (1.0f + expf(-v1));
            float conf = 1.0f / (1.0f + expf(-v4));
            float scls = 1.0f / (1.0f + expf(-v5));

            float x_c = clampp(sx), y_c = clampp(sy);
            float conf_c = clampp(conf), cls_c = clampp(scls);

            float txv = gx - floorf(gx), tyv = gy - floorf(gy);
            float twv = logf(fmaxf(gw, FEPS) / c_aw[bn]);
            float thv = logf(fmaxf(gh, FEPS) / c_ah[bn]);
            float bls = 2.0f - t2v * t3v;

            float bx = -txv * logf(x_c) - (1.0f - txv) * logf(1.0f - x_c);
            float by = -tyv * logf(y_c) - (1.0f - tyv) * logf(1.0f - y_c);
            float dw = v2 - twv, dh = v3 - thv;

            float pos = (bx + by) * bls
                      + 0.5f * (dw * dw + dh * dh) * bls
                      - logf(conf_c)        // bce(conf, 1) * mask
                      - logf(cls_c);        // bce(cls, 1) * mask (tcls = 1)

            // noobj correction: dense kernel adds -log(1-conf_c) to this cell iff
            // its max IoU <= 0.5 — recompute the same condition and cancel it.
            float pw = expf(v2) * c_aw[SUB + a];
            float ph = expf(v3) * c_ah[SUB + a];
            float px = sx + (float)gi, py = sy + (float)gj;
            float ax1 = px - pw * 0.5f, ay1 = py - ph * 0.5f;
            float ax2 = px + pw * 0.5f, ay2 = py + ph * 0.5f;
            float areaa = pw * ph;
            float worst = -1e30f;
            for (int u = 0; u < NT; ++u)
                worst = fmaxf(worst, iou_score(s_box[u], ax1, ay1, ax2, ay2, areaa));
            if (worst <= 0.0f) pos += logf(1.0f - conf_c);  // cancel noobj term

            extra = pos * (1.0f / (float)BSZ);
        }
        g_extra[b * NT + t] = extra;
    }
}

// ---------------- dense: noobj confidence loss over all cells ----------------
__global__ __launch_bounds__(DBLK) void dense_kernel(const float* __restrict__ in,
                                                     const float4* __restrict__ g_box,
                                                     float* __restrict__ g_part) {
    const int b   = blockIdx.y;
    const int tid = threadIdx.x;

    __shared__ float4 s_box[NT];
    if (tid < NT) s_box[tid] = g_box[b * NT + tid];
    __syncthreads();

    const int c0 = blockIdx.x * (DBLK * CPT) + tid;

    float ax1[CPT], ay1[CPT], ax2[CPT], ay2[CPT], areaa[CPT], nlog[CPT], worst[CPT];
    #pragma unroll
    for (int q = 0; q < CPT; ++q) {
        const int c = c0 + q * DBLK;
        ax1[q] = 0.f; ay1[q] = 0.f; ax2[q] = 0.f; ay2[q] = 0.f;
        areaa[q] = 0.f; nlog[q] = 0.f; worst[q] = -1e30f;
        if (c < CELLS) {
            const int a = c / CS;
            const int r = c - a * CS;
            const int j = r / IN_W;
            const int i = r - j * IN_W;
            const size_t base = ((size_t)b * 18 + (size_t)a * 6) * CS + r;
            float v0 = in[base];
            float v1 = in[base + CS];
            float v2 = in[base + 2 * CS];
            float v3 = in[base + 3 * CS];
            float v4 = in[base + 4 * CS];

            float sx   = 1.0f / (1.0f + expf(-v0));
            float sy   = 1.0f / (1.0f + expf(-v1));
            float conf = 1.0f / (1.0f + expf(-v4));
            float pw = expf(v2) * c_aw[SUB + a];
            float ph = expf(v3) * c_ah[SUB + a];
            float px = sx + (float)i, py = sy + (float)j;
            ax1[q] = px - pw * 0.5f; ay1[q] = py - ph * 0.5f;
            ax2[q] = px + pw * 0.5f; ay2[q] = py + ph * 0.5f;
            areaa[q] = pw * ph;
            nlog[q] = -logf(1.0f - clampp(conf));
        }
    }

    #pragma unroll 2
    for (int t = 0; t < NT; ++t) {
        float4 bx = s_box[t];
        #pragma unroll
        for (int q = 0; q < CPT; ++q)
            worst[q] = fmaxf(worst[q], iou_score(bx, ax1[q], ay1[q], ax2[q], ay2[q], areaa[q]));
    }

    float contrib = 0.0f;
    #pragma unroll
    for (int q = 0; q < CPT; ++q)
        contrib += (worst[q] <= 0.0f) ? nlog[q] : 0.0f;
    contrib *= (1.0f / (float)BSZ);

    // block reduction: wave64 shuffle + LDS across 4 waves
    for (int o = 32; o > 0; o >>= 1)
        contrib += __shfl_down(contrib, o, 64);

    __shared__ float s_part[DBLK / 64];
    if ((tid & 63) == 0) s_part[tid >> 6] = contrib;
    __syncthreads();
    if (tid == 0) {
        float tot = 0.f;
        #pragma unroll
        for (int k = 0; k < DBLK / 64; ++k) tot += s_part[k];
        g_part[b * NBX + blockIdx.x] = tot;   // plain write, no atomics, no memset
    }
}

// ---------------- final reduce ----------------
__global__ __launch_bounds__(256) void reduce_kernel(const float* __restrict__ g_extra,
                                                     const float* __restrict__ g_part,
                                                     float* __restrict__ out) {
    const int tid = threadIdx.x;
    float s = 0.0f;
    for (int i = tid; i < NPART; i += 256) s += g_part[i];
    for (int i = tid; i < BSZ * NT; i += 256) s += g_extra[i];

    for (int o = 32; o > 0; o >>= 1)
        s += __shfl_down(s, o, 64);

    __shared__ float s_part[4];
    if ((tid & 63) == 0) s_part[tid >> 6] = s;
    __syncthreads();
    if (tid == 0) out[0] = s_part[0] + s_part[1] + s_part[2] + s_part[3];
}

extern "C" void kernel_launch(void* const* d_in, const int* in_sizes, int n_in,
                              void* d_out, int out_size, void* d_ws, size_t ws_size,
                              hipStream_t stream) {
    const float* in  = (const float*)d_in[0];   // (16, 18, 104, 104) f32
    const float* tgt = (const float*)d_in[1];   // (16, 50, 5) f32
    float* out = (float*)d_out;

    // workspace layout (all overwritten every call — no zeroing needed)
    float4* g_box   = (float4*)d_ws;                             // 800 * 16 B
    float*  g_extra = (float*)d_ws + 4 * BSZ * NT;               // 800 * 4 B
    float*  g_part  = g_extra + BSZ * NT;                        // 1024 * 4 B

    prep_kernel<<<BSZ, 64, 0, stream>>>(in, tgt, g_box, g_extra);
    dense_kernel<<<dim3(NBX, BSZ), DBLK, 0, stream>>>(in, g_box, g_part);
    reduce_kernel<<<1, 256, 0, stream>>>(g_extra, g_part, out);
}

// Round 3
// 28.019 us; speedup vs baseline: 1.5846x; 1.1353x over previous
//
#include <hip/hip_runtime.h>
#include <math.h>

#define IN_H 104
#define IN_W 104
#define BSZ 16
#define NT 50
#define SUB 6
#define FEPS 1e-7f
#define CS (IN_H * IN_W)            // 10816
#define CELLS (3 * CS)              // 32448
#define DBLK 256
#define CPT 4
#define NBX ((CELLS + DBLK * CPT - 1) / (DBLK * CPT))   // 32
#define NPART (BSZ * NBX)           // 512

// scaled anchors = ANCHORS / 8  (stride = 832/104 = 8)
__constant__ float c_aw[9] = {1.25f, 2.0f, 4.125f, 3.75f, 7.75f, 7.375f, 14.5f, 19.5f, 46.625f};
__constant__ float c_ah[9] = {1.625f, 3.75f, 2.875f, 7.625f, 5.625f, 14.875f, 11.25f, 24.75f, 40.75f};

__device__ __forceinline__ float clampp(float v) {
    return fminf(fmaxf(v, FEPS), 1.0f - FEPS);
}

__device__ __forceinline__ float fsig(float v) {        // sigmoid, fast
    return __fdividef(1.0f, 1.0f + __expf(-v));
}

// >0  <=>  IoU(pred, box) > 0.5      (3*inter > areaA + areaB  <=>  2*inter > union)
__device__ __forceinline__ float iou_score(float4 bx, float ax1, float ay1,
                                           float ax2, float ay2, float areaa) {
    float mnx = fmaxf(ax1, bx.x), mny = fmaxf(ay1, bx.y);
    float mxx = fminf(ax2, bx.z), mxy = fminf(ay2, bx.w);
    float iw = fmaxf(mxx - mnx, 0.0f), ih = fmaxf(mxy - mny, 0.0f);
    float inter = iw * ih;
    float areab = (bx.z - bx.x) * (bx.w - bx.y);
    return 3.0f * inter - (areaa + areab);
}

// ---------------- fused: target staging + dense noobj + (block 0) positive losses ----
__global__ __launch_bounds__(DBLK) void yolo_fused_kernel(const float* __restrict__ in,
                                                          const float* __restrict__ tgt,
                                                          float* __restrict__ g_part,
                                                          float* __restrict__ g_extra) {
    const int b   = blockIdx.y;
    const int tid = threadIdx.x;
    const bool isb0 = (blockIdx.x == 0);

    __shared__ float4 s_box[NT];
    __shared__ int    s_code[NT];

    int   code = -1, bn = 0, gi = 0, gj = 0;
    float gx = 0.f, gy = 0.f, gw = 0.f, gh = 0.f, t2v = 0.f, t3v = 0.f;

    if (tid < NT) {
        const float* tp = tgt + (size_t)(b * NT + tid) * 5;
        float t0 = tp[0], t1 = tp[1];
        t2v = tp[2]; t3v = tp[3];
        gx = t0 * IN_W; gy = t1 * IN_H; gw = t2v * IN_W; gh = t3v * IN_H;
        s_box[tid] = make_float4(gx - gw * 0.5f, gy - gh * 0.5f,
                                 gx + gw * 0.5f, gy + gh * 0.5f);
        if (isb0) {
            float best = -1e30f;
            #pragma unroll
            for (int k = 0; k < 9; ++k) {
                float aw = c_aw[k], ah = c_ah[k];
                float inter = fminf(gw, aw) * fminf(gh, ah);
                float uni   = gw * gh + aw * ah - inter;
                float r = __fdividef(inter, uni);
                if (r > best) { best = r; bn = k; }
            }
            gi = (int)floorf(gx);
            gj = (int)floorf(gy);
            bool valid = (bn >= SUB) && (bn < SUB + 3) &&
                         (gj < IN_H) && (gi < IN_W) && (gi >= 0) && (gj >= 0);
            code = valid ? ((bn - SUB) * CS + gj * IN_W + gi) : -1;
            s_code[tid] = code;
        }
    }
    __syncthreads();

    // ---- dense noobj part: CPT cells per thread ----
    const int c0 = blockIdx.x * (DBLK * CPT) + tid;

    float ax1[CPT], ay1[CPT], ax2[CPT], ay2[CPT], areaa[CPT], nlog[CPT], worst[CPT];
    #pragma unroll
    for (int q = 0; q < CPT; ++q) {
        const int c = c0 + q * DBLK;
        ax1[q] = 0.f; ay1[q] = 0.f; ax2[q] = 0.f; ay2[q] = 0.f;
        areaa[q] = 0.f; nlog[q] = 0.f; worst[q] = -1e30f;
        if (c < CELLS) {
            const int a = c / CS;
            const int r = c - a * CS;
            const int j = r / IN_W;
            const int i = r - j * IN_W;
            const size_t base = ((size_t)b * 18 + (size_t)a * 6) * CS + r;
            float v0 = in[base];
            float v1 = in[base + CS];
            float v2 = in[base + 2 * CS];
            float v3 = in[base + 3 * CS];
            float v4 = in[base + 4 * CS];

            float sx   = fsig(v0);
            float sy   = fsig(v1);
            float conf = fsig(v4);
            float pw = __expf(v2) * c_aw[SUB + a];
            float ph = __expf(v3) * c_ah[SUB + a];
            float px = sx + (float)i, py = sy + (float)j;
            ax1[q] = px - pw * 0.5f; ay1[q] = py - ph * 0.5f;
            ax2[q] = px + pw * 0.5f; ay2[q] = py + ph * 0.5f;
            areaa[q] = pw * ph;
            nlog[q] = -__logf(1.0f - clampp(conf));
        }
    }

    #pragma unroll 2
    for (int t = 0; t < NT; ++t) {
        float4 bx = s_box[t];
        #pragma unroll
        for (int q = 0; q < CPT; ++q)
            worst[q] = fmaxf(worst[q], iou_score(bx, ax1[q], ay1[q], ax2[q], ay2[q], areaa[q]));
    }

    float contrib = 0.0f;
    #pragma unroll
    for (int q = 0; q < CPT; ++q)
        contrib += (worst[q] <= 0.0f) ? nlog[q] : 0.0f;
    contrib *= (1.0f / (float)BSZ);

    // ---- positive (masked-cell) losses: block 0 only ----
    if (isb0 && tid < NT) {
        bool winner = (code >= 0);
        for (int u = tid + 1; u < NT; ++u) winner = winner && (s_code[u] != code);

        float extra = 0.0f;
        if (winner) {
            const int a = bn - SUB;
            const size_t base = (((size_t)b * 18 + (size_t)a * 6) * IN_H + gj) * IN_W + gi;
            float v0 = in[base];
            float v1 = in[base + CS];
            float v2 = in[base + 2 * CS];
            float v3 = in[base + 3 * CS];
            float v4 = in[base + 4 * CS];
            float v5 = in[base + 5 * CS];

            float sx   = fsig(v0);
            float sy   = fsig(v1);
            float conf = fsig(v4);
            float scls = fsig(v5);

            float x_c = clampp(sx), y_c = clampp(sy);
            float conf_c = clampp(conf), cls_c = clampp(scls);

            float txv = gx - floorf(gx), tyv = gy - floorf(gy);
            float twv = __logf(__fdividef(fmaxf(gw, FEPS), c_aw[bn]));
            float thv = __logf(__fdividef(fmaxf(gh, FEPS), c_ah[bn]));
            float bls = 2.0f - t2v * t3v;

            float bx = -txv * __logf(x_c) - (1.0f - txv) * __logf(1.0f - x_c);
            float by = -tyv * __logf(y_c) - (1.0f - tyv) * __logf(1.0f - y_c);
            float dw = v2 - twv, dh = v3 - thv;

            float pos = (bx + by) * bls
                      + 0.5f * (dw * dw + dh * dh) * bls
                      - __logf(conf_c)      // bce(conf, 1) * mask
                      - __logf(cls_c);      // bce(cls, 1) * mask (tcls = 1)

            // noobj correction: cancel the dense kernel's term for this cell if it fires
            float pw = __expf(v2) * c_aw[SUB + a];
            float ph = __expf(v3) * c_ah[SUB + a];
            float px = sx + (float)gi, py = sy + (float)gj;
            float a1x = px - pw * 0.5f, a1y = py - ph * 0.5f;
            float a2x = px + pw * 0.5f, a2y = py + ph * 0.5f;
            float areap = pw * ph;
            float w2 = -1e30f;
            for (int u = 0; u < NT; ++u)
                w2 = fmaxf(w2, iou_score(s_box[u], a1x, a1y, a2x, a2y, areap));
            if (w2 <= 0.0f) pos += __logf(1.0f - conf_c);

            extra = pos * (1.0f / (float)BSZ);
        }
        g_extra[b * NT + tid] = extra;
    }

    // ---- block reduction: wave64 shuffle + LDS across 4 waves ----
    for (int o = 32; o > 0; o >>= 1)
        contrib += __shfl_down(contrib, o, 64);

    __shared__ float s_part[DBLK / 64];
    if ((tid & 63) == 0) s_part[tid >> 6] = contrib;
    __syncthreads();
    if (tid == 0) {
        float tot = 0.f;
        #pragma unroll
        for (int k = 0; k < DBLK / 64; ++k) tot += s_part[k];
        g_part[b * NBX + blockIdx.x] = tot;
    }
}

// ---------------- final reduce ----------------
__global__ __launch_bounds__(256) void reduce_kernel(const float* __restrict__ g_extra,
                                                     const float* __restrict__ g_part,
                                                     float* __restrict__ out) {
    const int tid = threadIdx.x;
    float s = 0.0f;
    for (int i = tid; i < NPART; i += 256) s += g_part[i];
    for (int i = tid; i < BSZ * NT; i += 256) s += g_extra[i];

    for (int o = 32; o > 0; o >>= 1)
        s += __shfl_down(s, o, 64);

    __shared__ float s_part[4];
    if ((tid & 63) == 0) s_part[tid >> 6] = s;
    __syncthreads();
    if (tid == 0) out[0] = s_part[0] + s_part[1] + s_part[2] + s_part[3];
}

extern "C" void kernel_launch(void* const* d_in, const int* in_sizes, int n_in,
                              void* d_out, int out_size, void* d_ws, size_t ws_size,
                              hipStream_t stream) {
    const float* in  = (const float*)d_in[0];   // (16, 18, 104, 104) f32
    const float* tgt = (const float*)d_in[1];   // (16, 50, 5) f32
    float* out = (float*)d_out;

    // workspace layout (fully overwritten every call — no zeroing needed)
    float* g_extra = (float*)d_ws;              // 800 floats
    float* g_part  = g_extra + BSZ * NT;        // 512 floats

    yolo_fused_kernel<<<dim3(NBX, BSZ), DBLK, 0, stream>>>(in, tgt, g_part, g_extra);
    reduce_kernel<<<1, 256, 0, stream>>>(g_extra, g_part, out);
}